// Round 15
// baseline (328.285 us; speedup 1.0000x reference)
//
#include <hip/hip_runtime.h>
#include <hip/hip_bf16.h>
#include <hip/hip_fp16.h>
#include <math.h>

typedef __hip_bfloat16 bf16;
#define NEG_SLOPE 0.2f
#define SFLAG (1 << 30)

typedef _Float16 f16x8 __attribute__((ext_vector_type(8)));
typedef float f32x4 __attribute__((ext_vector_type(4)));

// ====== dtype detect (block 0) + zero deg/scan-state =========================
__global__ void k_detect_zero(const unsigned short* __restrict__ x, int* __restrict__ flag,
                              int* __restrict__ zbase, int n) {
    for (int i = blockIdx.x * blockDim.x + threadIdx.x; i < n; i += gridDim.x * blockDim.x)
        zbase[i] = 0;
    if (blockIdx.x == 0) {
        __shared__ int cnt;
        if (threadIdx.x == 0) cnt = 0;
        __syncthreads();
        int local = 0;
        for (int i = threadIdx.x; i < 2048; i += blockDim.x) {
            unsigned short w = x[2 * i];
            int e = (w >> 7) & 0xFF;
            if (e >= 0x90) local++;
        }
        atomicAdd(&cnt, local);
        __syncthreads();
        if (threadIdx.x == 0) flag[0] = (cnt > 100) ? 1 : 0;  // 1 => inputs are f32
    }
}

#define NSEG 25
struct Seg { const void* src; int n; int off; };
struct Tab { Seg s[NSEG]; };

__device__ __forceinline__ float ldconv(const void* src, int i, int f32mode) {
    return f32mode ? ((const float*)src)[i]
                   : __bfloat162float(((const bf16*)src)[i]);
}

// ====== convert weights fp32 + transposed f16 weights + degree/rank ==========
__global__ void k_convert(Tab tab, float* __restrict__ dst, const int* __restrict__ flag,
                          const int* __restrict__ dstArr, int E, int N,
                          int* __restrict__ deg, int* __restrict__ rank,
                          const void* a2WlS, const void* a2WrS,
                          const void* gWlS, const void* gWrS,
                          __half* __restrict__ a2Wlt, __half* __restrict__ a2Wrt,
                          __half* __restrict__ gWlt, __half* __restrict__ gWrt) {
    int f32mode = flag[0];
    int gid = blockIdx.x * blockDim.x + threadIdx.x;
    int gsz = gridDim.x * blockDim.x;
    for (int s = 0; s < NSEG; s++) {
        Seg sg = tab.s[s];
        for (int i = gid; i < sg.n; i += gsz) {
            dst[sg.off + i] = ldconv(sg.src, i, f32mode);
        }
    }
    // transposed f16 weights: Wt[j][k] = W[k][j]
    for (int i = gid; i < 128 * 128; i += gsz) {
        int k = i >> 7, j = i & 127;
        a2Wlt[(size_t)j * 128 + k] = __float2half(ldconv(a2WlS, i, f32mode));
        a2Wrt[(size_t)j * 128 + k] = __float2half(ldconv(a2WrS, i, f32mode));
    }
    for (int i = gid; i < 128 * 32; i += gsz) {
        int k = i >> 5, j = i & 31;
        gWlt[(size_t)j * 128 + k] = __float2half(ldconv(gWlS, i, f32mode));
        gWrt[(size_t)j * 128 + k] = __float2half(ldconv(gWrS, i, f32mode));
    }
    int EA = E + N;
    for (int e = gid; e < EA; e += gsz) {
        int d = (e < E) ? dstArr[e] : (e - E);
        rank[e] = atomicAdd(&deg[d], 1);
    }
}

// ====== single-kernel chained-lookback exclusive scan ========================
__launch_bounds__(1024)
__global__ void k_scanf(const int* __restrict__ deg, int* __restrict__ offs,
                        int n, int* __restrict__ st, int nb) {
    __shared__ int ws[16];
    __shared__ int stot, sprev;
    int tile = blockIdx.x;
    int i = tile * 1024 + threadIdx.x;
    int lane = threadIdx.x & 63, wid = threadIdx.x >> 6;
    int v = (i < n) ? deg[i] : 0;
    int x = v;
    #pragma unroll
    for (int o = 1; o < 64; o <<= 1) {
        int y = __shfl_up(x, o);
        if (lane >= o) x += y;
    }
    if (lane == 63) ws[wid] = x;
    __syncthreads();
    if (wid == 0) {
        int w = (lane < 16) ? ws[lane] : 0;
        int s = w;
        #pragma unroll
        for (int o = 1; o < 16; o <<= 1) {
            int y = __shfl_up(s, o);
            if (lane >= o) s += y;
        }
        if (lane < 16) ws[lane] = s - w;
        if (lane == 15) stot = s;
    }
    __syncthreads();
    int local = ws[wid] + x - v;     // block-local exclusive
    if (threadIdx.x == 0) {
        int prev = 0;
        if (tile > 0) {
            int vv;
            while ((((vv = __hip_atomic_load(&st[tile - 1], __ATOMIC_ACQUIRE,
                                             __HIP_MEMORY_SCOPE_AGENT))) & SFLAG) == 0) {}
            prev = vv & ~SFLAG;
        }
        __hip_atomic_store(&st[tile], (prev + stot) | SFLAG, __ATOMIC_RELEASE,
                           __HIP_MEMORY_SCOPE_AGENT);
        sprev = prev;
        if (tile == nb - 1) offs[n] = prev + stot;
    }
    __syncthreads();
    if (i < n) offs[i] = sprev + local;
}

// ====== fused: CSR fill via rank (blocks >= EB) + embed+conv1-linear =========
__launch_bounds__(256)
__global__ void k_fill_embedlin(const int* __restrict__ srcArr, const int* __restrict__ dstArr,
                                int E, int N, const int* __restrict__ offs,
                                const int* __restrict__ rank, int* __restrict__ csr,
                                const void* __restrict__ xraw, const int* __restrict__ flag,
                                const float* __restrict__ aeW, const float* __restrict__ aeb,
                                const float* __restrict__ Wl, const float* __restrict__ bl,
                                const float* __restrict__ Wr, const float* __restrict__ br,
                                __half* __restrict__ outl, __half* __restrict__ outr,
                                int EB) {
    __shared__ float xs[100 * 36];
    __shared__ float axs[32 * 36];
    if (blockIdx.x >= EB) {
        int e = (blockIdx.x - EB) * 256 + threadIdx.x;
        int EA = E + N;
        if (e >= EA) return;
        int d, s;
        if (e < E) { d = dstArr[e]; s = srcArr[e]; } else { d = s = e - E; }
        csr[offs[d] + rank[e]] = s;     // no atomics: rank captured during count
        return;
    }
    constexpr int NTP = 36;
    int t = threadIdx.x, nb = blockIdx.x * 32;
    if (flag[0]) {
        const float4* x4 = (const float4*)xraw;
        for (int idx = t; idx < 32 * 25; idx += 256) {
            int node = idx / 25, k4 = idx % 25;
            float4 v = x4[(size_t)(nb + node) * 25 + k4];
            xs[(k4 * 4 + 0) * NTP + node] = v.x;
            xs[(k4 * 4 + 1) * NTP + node] = v.y;
            xs[(k4 * 4 + 2) * NTP + node] = v.z;
            xs[(k4 * 4 + 3) * NTP + node] = v.w;
        }
    } else {
        const ushort4* xu = (const ushort4*)xraw;
        for (int idx = t; idx < 32 * 25; idx += 256) {
            int node = idx / 25, k4 = idx % 25;
            ushort4 u = xu[(size_t)(nb + node) * 25 + k4];
            xs[(k4 * 4 + 0) * NTP + node] = __uint_as_float((unsigned)u.x << 16);
            xs[(k4 * 4 + 1) * NTP + node] = __uint_as_float((unsigned)u.y << 16);
            xs[(k4 * 4 + 2) * NTP + node] = __uint_as_float((unsigned)u.z << 16);
            xs[(k4 * 4 + 3) * NTP + node] = __uint_as_float((unsigned)u.w << 16);
        }
    }
    __syncthreads();
    {
        int j = t & 31, g0 = t >> 5;
        float a0 = 0.f, a1 = 0.f, a2 = 0.f, a3 = 0.f;
        #pragma unroll 10
        for (int k = 0; k < 100; k++) {
            float w = aeW[k * 32 + j];
            const float4 xv = *(const float4*)&xs[k * NTP + g0 * 4];
            a0 += w * xv.x; a1 += w * xv.y; a2 += w * xv.z; a3 += w * xv.w;
        }
        float bj = aeb[j];
        axs[j * NTP + g0 * 4 + 0] = fmaxf(a0 + bj, 0.f);
        axs[j * NTP + g0 * 4 + 1] = fmaxf(a1 + bj, 0.f);
        axs[j * NTP + g0 * 4 + 2] = fmaxf(a2 + bj, 0.f);
        axs[j * NTP + g0 * 4 + 3] = fmaxf(a3 + bj, 0.f);
    }
    __syncthreads();
    {
        int j = t & 63, g0 = t >> 6;
        float aL0[2][4], aL1[2][4], aR0[2][4], aR1[2][4];
        #pragma unroll
        for (int g = 0; g < 2; g++)
            #pragma unroll
            for (int c = 0; c < 4; c++) { aL0[g][c]=0.f; aL1[g][c]=0.f; aR0[g][c]=0.f; aR1[g][c]=0.f; }
        #pragma unroll 4
        for (int k = 0; k < 32; k++) {
            float wl0 = Wl[k * 128 + j];
            float wl1 = Wl[k * 128 + j + 64];
            float wr0 = Wr[k * 128 + j];
            float wr1 = Wr[k * 128 + j + 64];
            #pragma unroll
            for (int g = 0; g < 2; g++) {
                const float4 xv = *(const float4*)&axs[k * NTP + (g0 + g * 4) * 4];
                aL0[g][0] += wl0 * xv.x; aL0[g][1] += wl0 * xv.y; aL0[g][2] += wl0 * xv.z; aL0[g][3] += wl0 * xv.w;
                aL1[g][0] += wl1 * xv.x; aL1[g][1] += wl1 * xv.y; aL1[g][2] += wl1 * xv.z; aL1[g][3] += wl1 * xv.w;
                aR0[g][0] += wr0 * xv.x; aR0[g][1] += wr0 * xv.y; aR0[g][2] += wr0 * xv.z; aR0[g][3] += wr0 * xv.w;
                aR1[g][0] += wr1 * xv.x; aR1[g][1] += wr1 * xv.y; aR1[g][2] += wr1 * xv.z; aR1[g][3] += wr1 * xv.w;
            }
        }
        float bl0 = bl[j], bl1 = bl[j + 64], br0 = br[j], br1 = br[j + 64];
        #pragma unroll
        for (int g = 0; g < 2; g++) {
            int n0 = nb + (g0 + g * 4) * 4;
            #pragma unroll
            for (int c = 0; c < 4; c++) {
                size_t row = (size_t)(n0 + c) * 128;
                outl[row + j]      = __float2half(aL0[g][c] + bl0);
                outl[row + j + 64] = __float2half(aL1[g][c] + bl1);
                outr[row + j]      = __float2half(aR0[g][c] + br0);
                outr[row + j + 64] = __float2half(aR1[g][c] + br1);
            }
        }
    }
}

// ====== per-edge math: 8 lanes x 8 ch = 64 ch (half the heads) ===============
// per-head logit: head = 32 ch = 4 lanes -> shfl 1,2 only.
__device__ __forceinline__ void gproc8(f16x8 raw, bool valid, const float* xrd,
                                       const float* av, float* acc, float& sm) {
    float v[8];
    #pragma unroll
    for (int c = 0; c < 8; c++) v[c] = (float)raw[c];
    float p = 0.f;
    #pragma unroll
    for (int c = 0; c < 8; c++) {
        float u = v[c] + xrd[c];
        u = (u > 0.f) ? u : NEG_SLOPE * u;
        p += u * av[c];
    }
    p += __shfl_xor(p, 1);
    p += __shfl_xor(p, 2);          // per-head (4 lanes x 8ch = 32ch = one head)
    float w = __expf(fminf(p, 80.f));
    if (!valid) w = 0.f;
    sm += w;
    #pragma unroll
    for (int c = 0; c < 8; c++) acc[c] += w * v[c];
}

// serial fallback for deg > 64 (practically never taken on this input)
__device__ void gath_serial(const __half* __restrict__ xl, const int* __restrict__ csr,
                            int i0, int i1, int ch0, const float* xrd, const float* av,
                            float* acc, float& sm, int lane, int grp, int sub) {
    for (int base = i0; base < i1; base += 64) {
        int cnt = min(i1 - base, 64);
        int myv = (lane < cnt) ? csr[base + lane] : 0;
        int nbq = (cnt + 7) >> 3;
        for (int q = 0; q < nbq; q++) {
            int e = q * 8 + grp;
            int s = __shfl(myv, e & 63);
            f16x8 r = *(const f16x8*)(xl + (size_t)s * 128 + ch0 + sub * 8);
            gproc8(r, e < cnt, xrd, av, acc, sm);
        }
    }
}

// ====== half-head gather core: wave's 4 dsts interleaved =====================
struct G4 {
    float acc[4][8];
    float sm[4];
    float xrd[4][8];
    bool ok[4];
    int dbase;
};

__device__ __forceinline__ void gath4(G4& g, int ch0,
                                      const __half* __restrict__ xl,
                                      const __half* __restrict__ xr,
                                      const float* __restrict__ att,
                                      const int* __restrict__ offs,
                                      const int* __restrict__ csr,
                                      int nb, int N, float* av) {
    int t = threadIdx.x, wave = t >> 6, lane = t & 63;
    int grp = lane >> 3, sub = lane & 7;
    {
        const float4* t4 = (const float4*)(att + ch0 + sub * 8);
        float4 c = t4[0], e = t4[1];
        av[0]=c.x; av[1]=c.y; av[2]=c.z; av[3]=c.w;
        av[4]=e.x; av[5]=e.y; av[6]=e.z; av[7]=e.w;
    }
    g.dbase = nb + wave * 4;
    int i0[4], cnt[4], myv[4], nbq[4];
    bool fast = true;
    int nmax = 0;
    #pragma unroll
    for (int j = 0; j < 4; j++) {
        int d = g.dbase + j;
        g.ok[j] = d < N;
        i0[j] = g.ok[j] ? offs[d] : 0;
        int i1 = g.ok[j] ? offs[d + 1] : 0;
        cnt[j] = i1 - i0[j];
        if (cnt[j] > 64) fast = false;
        g.sm[j] = 0.f;
        #pragma unroll
        for (int c = 0; c < 8; c++) g.acc[j][c] = 0.f;
        if (g.ok[j]) {
            f16x8 hr = *(const f16x8*)(xr + (size_t)d * 128 + ch0 + sub * 8);
            #pragma unroll
            for (int c = 0; c < 8; c++) g.xrd[j][c] = (float)hr[c];
        }
    }
    if (fast) {
        #pragma unroll
        for (int j = 0; j < 4; j++) {
            myv[j] = (lane < cnt[j]) ? csr[i0[j] + lane] : 0;
            nbq[j] = (cnt[j] + 7) >> 3;
            nmax = max(nmax, nbq[j]);
        }
        for (int q = 0; q < nmax; q++) {
            f16x8 r[4];
            #pragma unroll
            for (int j = 0; j < 4; j++) {
                if (q < nbq[j]) {
                    int s = __shfl(myv[j], (q * 8 + grp) & 63);
                    r[j] = *(const f16x8*)(xl + (size_t)s * 128 + ch0 + sub * 8);
                }
            }
            #pragma unroll
            for (int j = 0; j < 4; j++)
                if (q < nbq[j])
                    gproc8(r[j], q * 8 + grp < cnt[j], g.xrd[j], av, g.acc[j], g.sm[j]);
        }
    } else {
        #pragma unroll
        for (int j = 0; j < 4; j++)
            if (g.ok[j])
                gath_serial(xl, csr, i0[j], i0[j] + cnt[j], ch0, g.xrd[j], av,
                            g.acc[j], g.sm[j], lane, grp, sub);
    }
    // merge the 8 edge-groups (lane bits 3..5)
    #pragma unroll
    for (int j = 0; j < 4; j++) {
        g.sm[j] += __shfl_xor(g.sm[j], 8);
        g.sm[j] += __shfl_xor(g.sm[j], 16);
        g.sm[j] += __shfl_xor(g.sm[j], 32);
        #pragma unroll
        for (int c = 0; c < 8; c++) {
            g.acc[j][c] += __shfl_xor(g.acc[j][c], 8);
            g.acc[j][c] += __shfl_xor(g.acc[j][c], 16);
            g.acc[j][c] += __shfl_xor(g.acc[j][c], 32);
        }
    }
}

// ====== pass A: gather ch 0-63 (heads 0,1), write half-result to global ======
__launch_bounds__(256)
__global__ void k_gatA(const __half* __restrict__ xl, const __half* __restrict__ xr,
                       const float* __restrict__ att,
                       const int* __restrict__ offs, const int* __restrict__ csr,
                       const float* __restrict__ bias, __half* __restrict__ gout, int N) {
    float av[8];
    G4 g;
    gath4(g, 0, xl, xr, att, offs, csr, blockIdx.x * 16, N, av);
    int lane = threadIdx.x & 63, grp = lane >> 3, sub = lane & 7;
    #pragma unroll
    for (int j = 0; j < 4; j++) {
        if (g.ok[j] && grp == 0) {
            float inv = 1.f / (g.sm[j] + 1e-16f);
            f16x8 o;
            #pragma unroll
            for (int c = 0; c < 8; c++)
                o[c] = (_Float16)fmaxf(g.acc[j][c] * inv + bias[sub * 8 + c], 0.f);
            *(f16x8*)(gout + (size_t)(g.dbase + j) * 64 + sub * 8) = o;
        }
    }
}

// ====== pass B + conv2 dual linear (MFMA): gather ch 64-127, fuse linear =====
__launch_bounds__(256)
__global__ void k_gatB_lin2(const __half* __restrict__ xl, const __half* __restrict__ xr,
                            const float* __restrict__ att,
                            const int* __restrict__ offs, const int* __restrict__ csr,
                            const float* __restrict__ bias, const __half* __restrict__ gA,
                            const __half* __restrict__ Wlt, const float* __restrict__ bl,
                            const __half* __restrict__ Wrt, const float* __restrict__ br,
                            __half* __restrict__ outl, __half* __restrict__ outr, int N) {
    __shared__ __align__(16) __half xsh[16 * 72];
    int nb = blockIdx.x * 16;
    float av[8];
    G4 g;
    gath4(g, 64, xl, xr, att, offs, csr, nb, N, av);
    int lane = threadIdx.x & 63, grp = lane >> 3, sub = lane & 7;
    #pragma unroll
    for (int j = 0; j < 4; j++) {
        if (g.ok[j] && grp == 0) {
            float inv = 1.f / (g.sm[j] + 1e-16f);
            f16x8 o;
            #pragma unroll
            for (int c = 0; c < 8; c++)
                o[c] = (_Float16)fmaxf(g.acc[j][c] * inv + bias[64 + sub * 8 + c], 0.f);
            *(f16x8*)&xsh[(g.dbase + j - nb) * 72 + sub * 8] = o;
        }
    }
    __syncthreads();

    int t = threadIdx.x;
    int wv = t >> 6;
    int quad = lane >> 4, n16 = lane & 15;
    int arow = min(nb + n16, N - 1);
    f16x8 a[4];
    a[0] = *(const f16x8*)&gA[(size_t)arow * 64 + 0 * 32 + quad * 8];
    a[1] = *(const f16x8*)&gA[(size_t)arow * 64 + 1 * 32 + quad * 8];
    a[2] = *(const f16x8*)&xsh[n16 * 72 + 0 * 32 + quad * 8];
    a[3] = *(const f16x8*)&xsh[n16 * 72 + 1 * 32 + quad * 8];

    int j0 = wv * 32;
    f32x4 aL0 = {0.f,0.f,0.f,0.f}, aL1 = {0.f,0.f,0.f,0.f};
    f32x4 aR0 = {0.f,0.f,0.f,0.f}, aR1 = {0.f,0.f,0.f,0.f};
    #pragma unroll
    for (int kt = 0; kt < 4; kt++) {
        int ko = kt * 32 + quad * 8;
        f16x8 b0 = *(const f16x8*)&Wlt[(size_t)(j0 + n16) * 128 + ko];
        f16x8 b1 = *(const f16x8*)&Wlt[(size_t)(j0 + 16 + n16) * 128 + ko];
        f16x8 b2 = *(const f16x8*)&Wrt[(size_t)(j0 + n16) * 128 + ko];
        f16x8 b3 = *(const f16x8*)&Wrt[(size_t)(j0 + 16 + n16) * 128 + ko];
        aL0 = __builtin_amdgcn_mfma_f32_16x16x32_f16(a[kt], b0, aL0, 0, 0, 0);
        aL1 = __builtin_amdgcn_mfma_f32_16x16x32_f16(a[kt], b1, aL1, 0, 0, 0);
        aR0 = __builtin_amdgcn_mfma_f32_16x16x32_f16(a[kt], b2, aR0, 0, 0, 0);
        aR1 = __builtin_amdgcn_mfma_f32_16x16x32_f16(a[kt], b3, aR1, 0, 0, 0);
    }
    float blj0 = bl[j0 + n16], blj1 = bl[j0 + 16 + n16];
    float brj0 = br[j0 + n16], brj1 = br[j0 + 16 + n16];
    #pragma unroll
    for (int r = 0; r < 4; r++) {
        int node = quad * 4 + r;
        if (nb + node >= N) continue;
        size_t row = (size_t)(nb + node) * 128;
        outl[row + j0 + n16]      = __float2half(aL0[r] + blj0);
        outl[row + j0 + 16 + n16] = __float2half(aL1[r] + blj1);
        outr[row + j0 + n16]      = __float2half(aR0[r] + brj0);
        outr[row + j0 + 16 + n16] = __float2half(aR1[r] + brj1);
    }
}

// ====== pass B + global linear FOUT=32 (MFMA) ================================
__launch_bounds__(256)
__global__ void k_gatB_ling(const __half* __restrict__ xl, const __half* __restrict__ xr,
                            const float* __restrict__ att,
                            const int* __restrict__ offs, const int* __restrict__ csr,
                            const float* __restrict__ bias, const __half* __restrict__ gA,
                            const __half* __restrict__ Wlt, const float* __restrict__ bl,
                            const __half* __restrict__ Wrt, const float* __restrict__ br,
                            __half* __restrict__ outl, __half* __restrict__ outr, int N) {
    __shared__ __align__(16) __half xsh[16 * 72];
    int nb = blockIdx.x * 16;
    float av[8];
    G4 g;
    gath4(g, 64, xl, xr, att, offs, csr, nb, N, av);
    int lane = threadIdx.x & 63, grp = lane >> 3, sub = lane & 7;
    #pragma unroll
    for (int j = 0; j < 4; j++) {
        if (g.ok[j] && grp == 0) {
            float inv = 1.f / (g.sm[j] + 1e-16f);
            f16x8 o;
            #pragma unroll
            for (int c = 0; c < 8; c++)
                o[c] = (_Float16)fmaxf(g.acc[j][c] * inv + bias[64 + sub * 8 + c], 0.f);
            *(f16x8*)&xsh[(g.dbase + j - nb) * 72 + sub * 8] = o;
        }
    }
    __syncthreads();

    int t = threadIdx.x;
    int wv = t >> 6;
    int quad = lane >> 4, n16 = lane & 15;
    int arow = min(nb + n16, N - 1);
    f16x8 a[4];
    a[0] = *(const f16x8*)&gA[(size_t)arow * 64 + 0 * 32 + quad * 8];
    a[1] = *(const f16x8*)&gA[(size_t)arow * 64 + 1 * 32 + quad * 8];
    a[2] = *(const f16x8*)&xsh[n16 * 72 + 0 * 32 + quad * 8];
    a[3] = *(const f16x8*)&xsh[n16 * 72 + 1 * 32 + quad * 8];

    // wave -> one 16x16 tile: wv0: L j0=0; wv1: L j0=16; wv2: R j0=0; wv3: R j0=16
    const __half* Wt = (wv < 2) ? Wlt : Wrt;
    int j0 = (wv & 1) * 16;
    f32x4 accv = {0.f,0.f,0.f,0.f};
    #pragma unroll
    for (int kt = 0; kt < 4; kt++) {
        f16x8 b = *(const f16x8*)&Wt[(size_t)(j0 + n16) * 128 + kt * 32 + quad * 8];
        accv = __builtin_amdgcn_mfma_f32_16x16x32_f16(a[kt], b, accv, 0, 0, 0);
    }
    float bj = ((wv < 2) ? bl : br)[j0 + n16];
    #pragma unroll
    for (int r = 0; r < 4; r++) {
        int node = quad * 4 + r;
        if (nb + node >= N) continue;
        size_t row = (size_t)(nb + node) * 32;
        if (wv < 2) outl[row + j0 + n16] = __float2half(accv[r] + bj);
        else        outr[row + j0 + n16] = __float2half(accv[r] + bj);
    }
}

// ===== tail: global-GAT gather for the 64 FOCAL dsts only + output head =====
__launch_bounds__(64)
__global__ void k_tailf(const __half* __restrict__ xl, const __half* __restrict__ xr,
                        const float* __restrict__ att,
                        const int* __restrict__ offs, const int* __restrict__ csr,
                        const float* __restrict__ gb, const int* __restrict__ focal,
                        const float* __restrict__ clf, const float* __restrict__ clW,
                        const float* __restrict__ clb, const float* __restrict__ fcW,
                        const float* __restrict__ fcb, void* __restrict__ out,
                        const int* __restrict__ flag) {
    __shared__ float comb[64];
    __shared__ float ssb[2];
    int b = blockIdx.x;
    int t = threadIdx.x;                  // 64
    int d = focal[b];
    int grp = t >> 3, sub = t & 7;        // 8 edge-groups x 8 lanes (4 ch each)
    int i0 = offs[d], i1 = offs[d + 1];

    float xrd[4], av[4], acc[4];
    {
        const __half2* hp = (const __half2*)(xr + (size_t)d * 32 + sub * 4);
        float2 f0 = __half22float2(hp[0]), f1 = __half22float2(hp[1]);
        xrd[0]=f0.x; xrd[1]=f0.y; xrd[2]=f1.x; xrd[3]=f1.y;
        float4 c = *(const float4*)(att + sub * 4);
        av[0]=c.x; av[1]=c.y; av[2]=c.z; av[3]=c.w;
    }
    #pragma unroll
    for (int c = 0; c < 4; c++) acc[c] = 0.f;
    float sm = 0.f;

    for (int i = i0 + grp; i < i1; i += 8) {
        float2 raw = *(const float2*)(xl + (size_t)csr[i] * 32 + sub * 4);
        const __half2* h = (const __half2*)&raw;
        float v[4];
        float2 f;
        f = __half22float2(h[0]); v[0] = f.x; v[1] = f.y;
        f = __half22float2(h[1]); v[2] = f.x; v[3] = f.y;
        float p = 0.f;
        #pragma unroll
        for (int c = 0; c < 4; c++) {
            float u = v[c] + xrd[c];
            u = (u > 0.f) ? u : NEG_SLOPE * u;
            p += u * av[c];
        }
        p += __shfl_xor(p, 1);
        p += __shfl_xor(p, 2);
        p += __shfl_xor(p, 4);       // H=1: logit over all 32 ch = 8 lanes
        float w = __expf(fminf(p, 80.f));
        sm += w;
        #pragma unroll
        for (int c = 0; c < 4; c++) acc[c] += w * v[c];
    }
    // merge 8 edge-groups
    sm += __shfl_xor(sm, 8); sm += __shfl_xor(sm, 16); sm += __shfl_xor(sm, 32);
    #pragma unroll
    for (int c = 0; c < 4; c++) {
        acc[c] += __shfl_xor(acc[c], 8);
        acc[c] += __shfl_xor(acc[c], 16);
        acc[c] += __shfl_xor(acc[c], 32);
    }
    if (grp == 0) {
        float inv = 1.f / (sm + 1e-16f);
        #pragma unroll
        for (int c = 0; c < 4; c++)
            comb[sub * 4 + c] = fmaxf(acc[c] * inv + gb[sub * 4 + c], 0.f);
    }
    if (t < 2) {
        float s = 0.f;
        for (int l = 0; l < 50; l++) s += clf[(size_t)b * 100 + l * 2 + t];
        ssb[t] = s / 50.f;
    }
    __syncthreads();
    if (t < 32) comb[32 + t] = ssb[0] * clW[t] + ssb[1] * clW[32 + t] + clb[t];
    __syncthreads();
    if (t < 60) {
        float a2 = fcb[t];
        #pragma unroll 16
        for (int k = 0; k < 64; k++) a2 += comb[k] * fcW[k * 60 + t];
        if (flag[0]) ((float*)out)[b * 60 + t] = a2;
        else ((bf16*)out)[b * 60 + t] = __float2bfloat16(a2);
    }
}

extern "C" void kernel_launch(void* const* d_in, const int* in_sizes, int n_in,
                              void* d_out, int out_size, void* d_ws, size_t ws_size,
                              hipStream_t stream) {
    const int* edge  = (const int*)d_in[1];
    const int* focal = (const int*)d_in[5];

    const int N = in_sizes[0] / 100;   // 20000
    const int E = in_sizes[1] / 2;     // 320000
    const int B = in_sizes[5];         // 64
    const int EA = E + N;
    const int* srcArr = edge;
    const int* dstArr = edge + E;

    // ---- conversion table: weights + centerlines -> fp32 in ws (x stays raw)
    const int idxs[NSEG] = {7,8,9,10,11,12,13,14,15,16,17,18,19,20,
                            35,36,37,38,39,40,41,42,43,44, 6};
    float* base = (float*)d_ws;
    int* flag = (int*)base;            // base[0..15] reserved
    float* wf = base + 16;
    Tab tab;
    int off[NSEG];
    int o = 0;
    for (int i = 0; i < NSEG; i++) {
        tab.s[i].src = d_in[idxs[i]];
        tab.s[i].n   = in_sizes[idxs[i]];
        tab.s[i].off = o;
        off[i] = o;
        o += in_sizes[idxs[i]];
    }
    const float* aeW  = wf + off[0],  *aeb  = wf + off[1];
    const float* a1Wl = wf + off[2],  *a1bl = wf + off[3];
    const float* a1Wr = wf + off[4],  *a1br = wf + off[5];
    const float* a1att= wf + off[6],  *a1b  = wf + off[7];
    const float* a2bl = wf + off[9];
    const float* a2br = wf + off[11];
    const float* a2att= wf + off[12], *a2b  = wf + off[13];
    const float* clW  = wf + off[14], *clb  = wf + off[15];
    const float* gbl  = wf + off[17];
    const float* gbr  = wf + off[19];
    const float* gatt = wf + off[20], *gb   = wf + off[21];
    const float* fcW  = wf + off[22], *fcb  = wf + off[23];
    const float* clf  = wf + off[24];

    // ---- remaining workspace (16B aligned) ----
    float* p = wf + o + ((4 - (o & 3)) & 3);
    __half* hxl1 = (__half*)p;      p += (size_t)N * 64;    // conv1 xl f16 [N,128]
    __half* hxr1 = (__half*)p;      p += (size_t)N * 64;    // conv1 xr f16 [N,128]
    __half* hxl2 = (__half*)p;      p += (size_t)N * 64;    // conv2 xl f16 [N,128]
    __half* hxr2 = (__half*)p;      p += (size_t)N * 64;    // conv2 xr f16 [N,128]
    __half* gCt  = (__half*)p;      p += (size_t)N * 32;    // pass-A half result f16 [N,64]
    __half* gxl  = (__half*)p;      p += (size_t)N * 16;    // global xl f16 [N,32]
    __half* gxr  = (__half*)p;      p += (size_t)N * 16;    // global xr f16 [N,32]
    int* deg    = (int*)p;          // [N]
    int* st     = deg + N;          // [32] scan lookback state
    int* offs   = st + 32;          // N+1
    int* rank   = offs + N + 1;     // EA
    int* csr    = rank + EA;        // EA (src node ids)
    // transposed f16 weights (16B aligned)
    uintptr_t up = (uintptr_t)(csr + EA);
    up = (up + 15) & ~(uintptr_t)15;
    __half* a2Wlt = (__half*)up;    // [128][128]
    __half* a2Wrt = a2Wlt + 16384;  // [128][128]
    __half* gWlt  = a2Wrt + 16384;  // [32][128]
    __half* gWrt  = gWlt + 4096;    // [32][128]

    const int NB = (N + 1023) / 1024;          // scan tiles (20)
    const int EB = N / 32;                     // embedlin blocks (625)
    const int FBLK = (EA + 255) / 256;         // fill blocks
    const int GT = (N + 15) / 16;              // gather tiles (1250)

    // ---- detect + zero deg/st ----
    k_detect_zero<<<64, 256, 0, stream>>>((const unsigned short*)d_in[0], flag, deg, N + 32);
    // ---- convert weights (+ f16 transposed) + degree count with rank capture
    k_convert<<<256, 256, 0, stream>>>(tab, wf, flag, dstArr, E, N, deg, rank,
                                       d_in[15], d_in[17], d_in[37], d_in[39],
                                       a2Wlt, a2Wrt, gWlt, gWrt);
    // ---- single-kernel lookback scan ----
    k_scanf<<<NB, 1024, 0, stream>>>(deg, offs, N, st, NB);
    // ---- CSR fill (rank trick) + fused embed+conv1-linear -> hxl1/hxr1 f16 --
    k_fill_embedlin<<<EB + FBLK, 256, 0, stream>>>(srcArr, dstArr, E, N, offs, rank, csr,
                                                   d_in[0], flag, aeW, aeb,
                                                   a1Wl, a1bl, a1Wr, a1br, hxl1, hxr1, EB);
    // ---- conv1: pass A (heads 0-1, L2-resident) then pass B + conv2 linear --
    k_gatA<<<GT, 256, 0, stream>>>(hxl1, hxr1, a1att, offs, csr, a1b, gCt, N);
    k_gatB_lin2<<<GT, 256, 0, stream>>>(hxl1, hxr1, a1att, offs, csr, a1b, gCt,
                                        a2Wlt, a2bl, a2Wrt, a2br, hxl2, hxr2, N);
    // ---- conv2: pass A then pass B + global linear ----
    k_gatA<<<GT, 256, 0, stream>>>(hxl2, hxr2, a2att, offs, csr, a2b, gCt, N);
    k_gatB_ling<<<GT, 256, 0, stream>>>(hxl2, hxr2, a2att, offs, csr, a2b, gCt,
                                        gWlt, gbl, gWrt, gbr, gxl, gxr, N);
    // ---- tail: global gather for the 64 focal dsts + head ----
    k_tailf<<<B, 64, 0, stream>>>(gxl, gxr, gatt, offs, csr, gb, focal,
                                  clf, clW, clb, fcW, fcb, d_out, flag);
}

// Round 16
// 292.474 us; speedup vs baseline: 1.1224x; 1.1224x over previous
//
#include <hip/hip_runtime.h>
#include <hip/hip_bf16.h>
#include <hip/hip_fp16.h>
#include <math.h>

typedef __hip_bfloat16 bf16;
#define NEG_SLOPE 0.2f
#define SFLAG (1 << 30)

typedef _Float16 f16x8 __attribute__((ext_vector_type(8)));
typedef float f32x4 __attribute__((ext_vector_type(4)));

// ====== dtype detect (block 0) + zero deg/scan-state =========================
__global__ void k_detect_zero(const unsigned short* __restrict__ x, int* __restrict__ flag,
                              int* __restrict__ zbase, int n) {
    for (int i = blockIdx.x * blockDim.x + threadIdx.x; i < n; i += gridDim.x * blockDim.x)
        zbase[i] = 0;
    if (blockIdx.x == 0) {
        __shared__ int cnt;
        if (threadIdx.x == 0) cnt = 0;
        __syncthreads();
        int local = 0;
        for (int i = threadIdx.x; i < 2048; i += blockDim.x) {
            unsigned short w = x[2 * i];
            int e = (w >> 7) & 0xFF;
            if (e >= 0x90) local++;
        }
        atomicAdd(&cnt, local);
        __syncthreads();
        if (threadIdx.x == 0) flag[0] = (cnt > 100) ? 1 : 0;  // 1 => inputs are f32
    }
}

#define NSEG 25
struct Seg { const void* src; int n; int off; };
struct Tab { Seg s[NSEG]; };

__device__ __forceinline__ float ldconv(const void* src, int i, int f32mode) {
    return f32mode ? ((const float*)src)[i]
                   : __bfloat162float(((const bf16*)src)[i]);
}

// ====== convert weights fp32 + transposed f16 weights + degree/rank ==========
__global__ void k_convert(Tab tab, float* __restrict__ dst, const int* __restrict__ flag,
                          const int* __restrict__ dstArr, int E, int N,
                          int* __restrict__ deg, int* __restrict__ rank,
                          const void* a2WlS, const void* a2WrS,
                          const void* gWlS, const void* gWrS,
                          __half* __restrict__ a2Wlt, __half* __restrict__ a2Wrt,
                          __half* __restrict__ gWlt, __half* __restrict__ gWrt) {
    int f32mode = flag[0];
    int gid = blockIdx.x * blockDim.x + threadIdx.x;
    int gsz = gridDim.x * blockDim.x;
    for (int s = 0; s < NSEG; s++) {
        Seg sg = tab.s[s];
        for (int i = gid; i < sg.n; i += gsz) {
            dst[sg.off + i] = ldconv(sg.src, i, f32mode);
        }
    }
    // transposed f16 weights: Wt[j][k] = W[k][j]
    for (int i = gid; i < 128 * 128; i += gsz) {
        int k = i >> 7, j = i & 127;
        a2Wlt[(size_t)j * 128 + k] = __float2half(ldconv(a2WlS, i, f32mode));
        a2Wrt[(size_t)j * 128 + k] = __float2half(ldconv(a2WrS, i, f32mode));
    }
    for (int i = gid; i < 128 * 32; i += gsz) {
        int k = i >> 5, j = i & 31;
        gWlt[(size_t)j * 128 + k] = __float2half(ldconv(gWlS, i, f32mode));
        gWrt[(size_t)j * 128 + k] = __float2half(ldconv(gWrS, i, f32mode));
    }
    int EA = E + N;
    for (int e = gid; e < EA; e += gsz) {
        int d = (e < E) ? dstArr[e] : (e - E);
        rank[e] = atomicAdd(&deg[d], 1);
    }
}

// ====== single-kernel chained-lookback exclusive scan ========================
__launch_bounds__(1024)
__global__ void k_scanf(const int* __restrict__ deg, int* __restrict__ offs,
                        int n, int* __restrict__ st, int nb) {
    __shared__ int ws[16];
    __shared__ int stot, sprev;
    int tile = blockIdx.x;
    int i = tile * 1024 + threadIdx.x;
    int lane = threadIdx.x & 63, wid = threadIdx.x >> 6;
    int v = (i < n) ? deg[i] : 0;
    int x = v;
    #pragma unroll
    for (int o = 1; o < 64; o <<= 1) {
        int y = __shfl_up(x, o);
        if (lane >= o) x += y;
    }
    if (lane == 63) ws[wid] = x;
    __syncthreads();
    if (wid == 0) {
        int w = (lane < 16) ? ws[lane] : 0;
        int s = w;
        #pragma unroll
        for (int o = 1; o < 16; o <<= 1) {
            int y = __shfl_up(s, o);
            if (lane >= o) s += y;
        }
        if (lane < 16) ws[lane] = s - w;
        if (lane == 15) stot = s;
    }
    __syncthreads();
    int local = ws[wid] + x - v;     // block-local exclusive
    if (threadIdx.x == 0) {
        int prev = 0;
        if (tile > 0) {
            int vv;
            while ((((vv = __hip_atomic_load(&st[tile - 1], __ATOMIC_ACQUIRE,
                                             __HIP_MEMORY_SCOPE_AGENT))) & SFLAG) == 0) {}
            prev = vv & ~SFLAG;
        }
        __hip_atomic_store(&st[tile], (prev + stot) | SFLAG, __ATOMIC_RELEASE,
                           __HIP_MEMORY_SCOPE_AGENT);
        sprev = prev;
        if (tile == nb - 1) offs[n] = prev + stot;
    }
    __syncthreads();
    if (i < n) offs[i] = sprev + local;
}

// ====== fused: CSR fill via rank (blocks >= EB) + embed+conv1-linear =========
__launch_bounds__(256)
__global__ void k_fill_embedlin(const int* __restrict__ srcArr, const int* __restrict__ dstArr,
                                int E, int N, const int* __restrict__ offs,
                                const int* __restrict__ rank, int* __restrict__ csr,
                                const void* __restrict__ xraw, const int* __restrict__ flag,
                                const float* __restrict__ aeW, const float* __restrict__ aeb,
                                const float* __restrict__ Wl, const float* __restrict__ bl,
                                const float* __restrict__ Wr, const float* __restrict__ br,
                                __half* __restrict__ outl, float* __restrict__ outr,
                                int EB) {
    __shared__ float xs[100 * 36];
    __shared__ float axs[32 * 36];
    if (blockIdx.x >= EB) {
        int e = (blockIdx.x - EB) * 256 + threadIdx.x;
        int EA = E + N;
        if (e >= EA) return;
        int d, s;
        if (e < E) { d = dstArr[e]; s = srcArr[e]; } else { d = s = e - E; }
        csr[offs[d] + rank[e]] = s;     // no atomics: rank captured during count
        return;
    }
    constexpr int NTP = 36;
    int t = threadIdx.x, nb = blockIdx.x * 32;
    if (flag[0]) {
        const float4* x4 = (const float4*)xraw;
        for (int idx = t; idx < 32 * 25; idx += 256) {
            int node = idx / 25, k4 = idx % 25;
            float4 v = x4[(size_t)(nb + node) * 25 + k4];
            xs[(k4 * 4 + 0) * NTP + node] = v.x;
            xs[(k4 * 4 + 1) * NTP + node] = v.y;
            xs[(k4 * 4 + 2) * NTP + node] = v.z;
            xs[(k4 * 4 + 3) * NTP + node] = v.w;
        }
    } else {
        const ushort4* xu = (const ushort4*)xraw;
        for (int idx = t; idx < 32 * 25; idx += 256) {
            int node = idx / 25, k4 = idx % 25;
            ushort4 u = xu[(size_t)(nb + node) * 25 + k4];
            xs[(k4 * 4 + 0) * NTP + node] = __uint_as_float((unsigned)u.x << 16);
            xs[(k4 * 4 + 1) * NTP + node] = __uint_as_float((unsigned)u.y << 16);
            xs[(k4 * 4 + 2) * NTP + node] = __uint_as_float((unsigned)u.z << 16);
            xs[(k4 * 4 + 3) * NTP + node] = __uint_as_float((unsigned)u.w << 16);
        }
    }
    __syncthreads();
    {
        int j = t & 31, g0 = t >> 5;
        float a0 = 0.f, a1 = 0.f, a2 = 0.f, a3 = 0.f;
        #pragma unroll 10
        for (int k = 0; k < 100; k++) {
            float w = aeW[k * 32 + j];
            const float4 xv = *(const float4*)&xs[k * NTP + g0 * 4];
            a0 += w * xv.x; a1 += w * xv.y; a2 += w * xv.z; a3 += w * xv.w;
        }
        float bj = aeb[j];
        axs[j * NTP + g0 * 4 + 0] = fmaxf(a0 + bj, 0.f);
        axs[j * NTP + g0 * 4 + 1] = fmaxf(a1 + bj, 0.f);
        axs[j * NTP + g0 * 4 + 2] = fmaxf(a2 + bj, 0.f);
        axs[j * NTP + g0 * 4 + 3] = fmaxf(a3 + bj, 0.f);
    }
    __syncthreads();
    {
        int j = t & 63, g0 = t >> 6;
        float aL0[2][4], aL1[2][4], aR0[2][4], aR1[2][4];
        #pragma unroll
        for (int g = 0; g < 2; g++)
            #pragma unroll
            for (int c = 0; c < 4; c++) { aL0[g][c]=0.f; aL1[g][c]=0.f; aR0[g][c]=0.f; aR1[g][c]=0.f; }
        #pragma unroll 4
        for (int k = 0; k < 32; k++) {
            float wl0 = Wl[k * 128 + j];
            float wl1 = Wl[k * 128 + j + 64];
            float wr0 = Wr[k * 128 + j];
            float wr1 = Wr[k * 128 + j + 64];
            #pragma unroll
            for (int g = 0; g < 2; g++) {
                const float4 xv = *(const float4*)&axs[k * NTP + (g0 + g * 4) * 4];
                aL0[g][0] += wl0 * xv.x; aL0[g][1] += wl0 * xv.y; aL0[g][2] += wl0 * xv.z; aL0[g][3] += wl0 * xv.w;
                aL1[g][0] += wl1 * xv.x; aL1[g][1] += wl1 * xv.y; aL1[g][2] += wl1 * xv.z; aL1[g][3] += wl1 * xv.w;
                aR0[g][0] += wr0 * xv.x; aR0[g][1] += wr0 * xv.y; aR0[g][2] += wr0 * xv.z; aR0[g][3] += wr0 * xv.w;
                aR1[g][0] += wr1 * xv.x; aR1[g][1] += wr1 * xv.y; aR1[g][2] += wr1 * xv.z; aR1[g][3] += wr1 * xv.w;
            }
        }
        float bl0 = bl[j], bl1 = bl[j + 64], br0 = br[j], br1 = br[j + 64];
        #pragma unroll
        for (int g = 0; g < 2; g++) {
            int n0 = nb + (g0 + g * 4) * 4;
            #pragma unroll
            for (int c = 0; c < 4; c++) {
                size_t row = (size_t)(n0 + c) * 128;
                outl[row + j]      = __float2half(aL0[g][c] + bl0);
                outl[row + j + 64] = __float2half(aL1[g][c] + bl1);
                outr[row + j]      = aR0[g][c] + br0;
                outr[row + j + 64] = aR1[g][c] + br1;
            }
        }
    }
}

// ====== per-edge math (16-lane group, 8 channels/lane) =======================
__device__ __forceinline__ void gat_proc(float4 raw, bool valid,
                                         const float* xrd, const float* av,
                                         float* acc, float& sm) {
    const __half2* h = (const __half2*)&raw;
    float v[8];
    float2 f;
    f = __half22float2(h[0]); v[0] = f.x; v[1] = f.y;
    f = __half22float2(h[1]); v[2] = f.x; v[3] = f.y;
    f = __half22float2(h[2]); v[4] = f.x; v[5] = f.y;
    f = __half22float2(h[3]); v[6] = f.x; v[7] = f.y;
    float p = 0.f;
    #pragma unroll
    for (int c = 0; c < 8; c++) {
        float u = v[c] + xrd[c];
        u = (u > 0.f) ? u : NEG_SLOPE * u;
        p += u * av[c];
    }
    p += __shfl_xor(p, 1);
    p += __shfl_xor(p, 2);
    p += __shfl_xor(p, 4);
    p += __shfl_xor(p, 8);
    float w = __expf(fminf(p, 80.f));
    if (!valid) w = 0.f;
    sm += w;
    #pragma unroll
    for (int c = 0; c < 8; c++) acc[c] += w * v[c];
}

// serial fallback for deg > 64 (practically never taken on this input)
__device__ void gat_one_serial(const __half* __restrict__ xl,
                               const int* __restrict__ csr, int i0, int i1,
                               const float* xrd, const float* av,
                               float* acc, float& sm, int lane, int grp, int sub) {
    for (int base = i0; base < i1; base += 64) {
        int cnt = min(i1 - base, 64);
        int myv = (lane < cnt) ? csr[base + lane] : 0;
        int nbq = (cnt + 15) >> 4;
        for (int q = 0; q < nbq; q++) {
            int e0 = q * 16 + grp;
            int s0 = __shfl(myv, e0 & 63);
            int s1 = __shfl(myv, (e0 + 4) & 63);
            int s2 = __shfl(myv, (e0 + 8) & 63);
            int s3 = __shfl(myv, (e0 + 12) & 63);
            float4 r0 = *(const float4*)(xl + (size_t)s0 * 128 + sub * 8);
            float4 r1 = *(const float4*)(xl + (size_t)s1 * 128 + sub * 8);
            float4 r2 = *(const float4*)(xl + (size_t)s2 * 128 + sub * 8);
            float4 r3 = *(const float4*)(xl + (size_t)s3 * 128 + sub * 8);
            gat_proc(r0, e0 < cnt, xrd, av, acc, sm);
            gat_proc(r1, e0 + 4 < cnt, xrd, av, acc, sm);
            gat_proc(r2, e0 + 8 < cnt, xrd, av, acc, sm);
            gat_proc(r3, e0 + 12 < cnt, xrd, av, acc, sm);
        }
    }
}

// ====== GAT H=4 gather of a 16-dst tile into LDS (fp16, node-major) ==========
// xsh layout: xsh[node * 136 + ch], node in [0,16), ch in [0,128). 4.35 KB.
__device__ __forceinline__ void gat16_to_lds(__half* xsh,
                                             const __half* __restrict__ xl,
                                             const float* __restrict__ xr,
                                             const float* __restrict__ att,
                                             const int* __restrict__ offs,
                                             const int* __restrict__ csr,
                                             const float* __restrict__ bias,
                                             int nb, int N) {
    int t = threadIdx.x;
    int wave = t >> 6, lane = t & 63;
    int grp = lane >> 4, sub = lane & 15;     // 4 edge-groups x 16 lanes
    float av[8];
    {
        const float4* t4 = (const float4*)(att + sub * 8);
        float4 c = t4[0], e = t4[1];
        av[0]=c.x; av[1]=c.y; av[2]=c.z; av[3]=c.w;
        av[4]=e.x; av[5]=e.y; av[6]=e.z; av[7]=e.w;
    }
    for (int it = 0; it < 4; it += 2) {
        int d0 = nb + wave * 4 + it;
        int d1 = d0 + 1;
        bool ok0 = d0 < N, ok1 = d1 < N;
        int i00 = ok0 ? offs[d0] : 0, i01 = ok0 ? offs[d0 + 1] : 0;
        int i10 = ok1 ? offs[d1] : 0, i11 = ok1 ? offs[d1 + 1] : 0;
        int cnt0 = i01 - i00, cnt1 = i11 - i10;

        float xrd0[8], xrd1[8], acc0[8], acc1[8];
        float sm0 = 0.f, sm1 = 0.f;
        #pragma unroll
        for (int c = 0; c < 8; c++) { acc0[c] = 0.f; acc1[c] = 0.f; }
        if (ok0) {
            const float4* p4 = (const float4*)(xr + (size_t)d0 * 128 + sub * 8);
            float4 a = p4[0], b = p4[1];
            xrd0[0]=a.x; xrd0[1]=a.y; xrd0[2]=a.z; xrd0[3]=a.w;
            xrd0[4]=b.x; xrd0[5]=b.y; xrd0[6]=b.z; xrd0[7]=b.w;
        }
        if (ok1) {
            const float4* p4 = (const float4*)(xr + (size_t)d1 * 128 + sub * 8);
            float4 a = p4[0], b = p4[1];
            xrd1[0]=a.x; xrd1[1]=a.y; xrd1[2]=a.z; xrd1[3]=a.w;
            xrd1[4]=b.x; xrd1[5]=b.y; xrd1[6]=b.z; xrd1[7]=b.w;
        }

        if (cnt0 <= 64 && cnt1 <= 64) {
            int myv0 = (lane < cnt0) ? csr[i00 + lane] : 0;
            int myv1 = (lane < cnt1) ? csr[i10 + lane] : 0;
            int nb0 = (cnt0 + 15) >> 4, nb1 = (cnt1 + 15) >> 4;
            int nbm = max(nb0, nb1);
            for (int q = 0; q < nbm; q++) {
                int e0 = q * 16 + grp;
                float4 r00, r01, r02, r03, r10, r11, r12, r13;
                if (q < nb0) {
                    int s0 = __shfl(myv0, e0 & 63);
                    int s1 = __shfl(myv0, (e0 + 4) & 63);
                    int s2 = __shfl(myv0, (e0 + 8) & 63);
                    int s3 = __shfl(myv0, (e0 + 12) & 63);
                    r00 = *(const float4*)(xl + (size_t)s0 * 128 + sub * 8);
                    r01 = *(const float4*)(xl + (size_t)s1 * 128 + sub * 8);
                    r02 = *(const float4*)(xl + (size_t)s2 * 128 + sub * 8);
                    r03 = *(const float4*)(xl + (size_t)s3 * 128 + sub * 8);
                }
                if (q < nb1) {
                    int s0 = __shfl(myv1, e0 & 63);
                    int s1 = __shfl(myv1, (e0 + 4) & 63);
                    int s2 = __shfl(myv1, (e0 + 8) & 63);
                    int s3 = __shfl(myv1, (e0 + 12) & 63);
                    r10 = *(const float4*)(xl + (size_t)s0 * 128 + sub * 8);
                    r11 = *(const float4*)(xl + (size_t)s1 * 128 + sub * 8);
                    r12 = *(const float4*)(xl + (size_t)s2 * 128 + sub * 8);
                    r13 = *(const float4*)(xl + (size_t)s3 * 128 + sub * 8);
                }
                if (q < nb0) {
                    gat_proc(r00, e0 < cnt0, xrd0, av, acc0, sm0);
                    gat_proc(r01, e0 + 4 < cnt0, xrd0, av, acc0, sm0);
                    gat_proc(r02, e0 + 8 < cnt0, xrd0, av, acc0, sm0);
                    gat_proc(r03, e0 + 12 < cnt0, xrd0, av, acc0, sm0);
                }
                if (q < nb1) {
                    gat_proc(r10, e0 < cnt1, xrd1, av, acc1, sm1);
                    gat_proc(r11, e0 + 4 < cnt1, xrd1, av, acc1, sm1);
                    gat_proc(r12, e0 + 8 < cnt1, xrd1, av, acc1, sm1);
                    gat_proc(r13, e0 + 12 < cnt1, xrd1, av, acc1, sm1);
                }
            }
        } else {
            if (ok0) gat_one_serial(xl, csr, i00, i01, xrd0, av, acc0, sm0, lane, grp, sub);
            if (ok1) gat_one_serial(xl, csr, i10, i11, xrd1, av, acc1, sm1, lane, grp, sub);
        }

        // full butterfly merge: all 4 groups end with the sums
        sm0 += __shfl_xor(sm0, 16); sm0 += __shfl_xor(sm0, 32);
        sm1 += __shfl_xor(sm1, 16); sm1 += __shfl_xor(sm1, 32);
        #pragma unroll
        for (int c = 0; c < 8; c++) {
            acc0[c] += __shfl_xor(acc0[c], 16); acc0[c] += __shfl_xor(acc0[c], 32);
            acc1[c] += __shfl_xor(acc1[c], 16); acc1[c] += __shfl_xor(acc1[c], 32);
        }
        // write fp16 node-major: all 64 lanes, 2 channels each
        int c2 = grp * 2;
        int ch0 = sub * 8 + c2;
        if (ok0) {
            float inv = 1.f / (sm0 + 1e-16f);
            int node = d0 - nb;
            __half2 hv;
            hv.x = __float2half(fmaxf(acc0[c2] * inv + bias[ch0], 0.f));
            hv.y = __float2half(fmaxf(acc0[c2 + 1] * inv + bias[ch0 + 1], 0.f));
            *(__half2*)&xsh[node * 136 + ch0] = hv;
        }
        if (ok1) {
            float inv = 1.f / (sm1 + 1e-16f);
            int node = d1 - nb;
            __half2 hv;
            hv.x = __float2half(fmaxf(acc1[c2] * inv + bias[ch0], 0.f));
            hv.y = __float2half(fmaxf(acc1[c2 + 1] * inv + bias[ch0 + 1], 0.f));
            *(__half2*)&xsh[node * 136 + ch0] = hv;
        }
    }
}

// ====== fused: conv1 gather (16-dst tile) -> conv2 dual linear via MFMA ======
__launch_bounds__(256)
__global__ void k_gatlin(const __half* __restrict__ xl, const float* __restrict__ xr,
                         const float* __restrict__ att,
                         const int* __restrict__ offs, const int* __restrict__ csr,
                         const float* __restrict__ bias,
                         const __half* __restrict__ Wlt, const float* __restrict__ bl,
                         const __half* __restrict__ Wrt, const float* __restrict__ br,
                         __half* __restrict__ outl, float* __restrict__ outr, int N) {
    __shared__ __align__(16) __half xsh[16 * 136];
    int nb = blockIdx.x * 16;
    gat16_to_lds(xsh, xl, xr, att, offs, csr, bias, nb, N);
    __syncthreads();

    int t = threadIdx.x;
    int lane = t & 63, wv = t >> 6;
    int quad = lane >> 4, n16 = lane & 15;
    // A fragments: A[m=lane&15][k=quad*8+i], 4 k-tiles of 32
    f16x8 a[4];
    #pragma unroll
    for (int kt = 0; kt < 4; kt++)
        a[kt] = *(const f16x8*)&xsh[n16 * 136 + kt * 32 + quad * 8];

    int j0 = wv * 32;   // this wave's 32 output columns (two 16-tiles), for L and R
    f32x4 aL0 = {0.f,0.f,0.f,0.f}, aL1 = {0.f,0.f,0.f,0.f};
    f32x4 aR0 = {0.f,0.f,0.f,0.f}, aR1 = {0.f,0.f,0.f,0.f};
    #pragma unroll
    for (int kt = 0; kt < 4; kt++) {
        int ko = kt * 32 + quad * 8;
        f16x8 b0 = *(const f16x8*)&Wlt[(size_t)(j0 + n16) * 128 + ko];
        f16x8 b1 = *(const f16x8*)&Wlt[(size_t)(j0 + 16 + n16) * 128 + ko];
        f16x8 b2 = *(const f16x8*)&Wrt[(size_t)(j0 + n16) * 128 + ko];
        f16x8 b3 = *(const f16x8*)&Wrt[(size_t)(j0 + 16 + n16) * 128 + ko];
        aL0 = __builtin_amdgcn_mfma_f32_16x16x32_f16(a[kt], b0, aL0, 0, 0, 0);
        aL1 = __builtin_amdgcn_mfma_f32_16x16x32_f16(a[kt], b1, aL1, 0, 0, 0);
        aR0 = __builtin_amdgcn_mfma_f32_16x16x32_f16(a[kt], b2, aR0, 0, 0, 0);
        aR1 = __builtin_amdgcn_mfma_f32_16x16x32_f16(a[kt], b3, aR1, 0, 0, 0);
    }
    float blj0 = bl[j0 + n16], blj1 = bl[j0 + 16 + n16];
    float brj0 = br[j0 + n16], brj1 = br[j0 + 16 + n16];
    #pragma unroll
    for (int r = 0; r < 4; r++) {
        int node = quad * 4 + r;        // D row = node
        if (nb + node >= N) continue;
        size_t row = (size_t)(nb + node) * 128;
        outl[row + j0 + n16]      = __float2half(aL0[r] + blj0);
        outl[row + j0 + 16 + n16] = __float2half(aL1[r] + blj1);
        outr[row + j0 + n16]      = aR0[r] + brj0;
        outr[row + j0 + 16 + n16] = aR1[r] + brj1;
    }
}

// ====== fused: conv2 gather (16-dst tile) -> global linear (FOUT=32) MFMA ====
__launch_bounds__(256)
__global__ void k_gatling(const __half* __restrict__ xl, const float* __restrict__ xr,
                          const float* __restrict__ att,
                          const int* __restrict__ offs, const int* __restrict__ csr,
                          const float* __restrict__ bias,
                          const __half* __restrict__ Wlt, const float* __restrict__ bl,
                          const __half* __restrict__ Wrt, const float* __restrict__ br,
                          __half* __restrict__ outl, float* __restrict__ outr, int N) {
    __shared__ __align__(16) __half xsh[16 * 136];
    int nb = blockIdx.x * 16;
    gat16_to_lds(xsh, xl, xr, att, offs, csr, bias, nb, N);
    __syncthreads();

    int t = threadIdx.x;
    int lane = t & 63, wv = t >> 6;
    int quad = lane >> 4, n16 = lane & 15;
    f16x8 a[4];
    #pragma unroll
    for (int kt = 0; kt < 4; kt++)
        a[kt] = *(const f16x8*)&xsh[n16 * 136 + kt * 32 + quad * 8];

    // wave -> one 16x16 tile: wv 0: L j0=0; 1: L j0=16; 2: R j0=0; 3: R j0=16
    const __half* Wt = (wv < 2) ? Wlt : Wrt;
    int j0 = (wv & 1) * 16;
    f32x4 accv = {0.f,0.f,0.f,0.f};
    #pragma unroll
    for (int kt = 0; kt < 4; kt++) {
        f16x8 b = *(const f16x8*)&Wt[(size_t)(j0 + n16) * 128 + kt * 32 + quad * 8];
        accv = __builtin_amdgcn_mfma_f32_16x16x32_f16(a[kt], b, accv, 0, 0, 0);
    }
    float bj = ((wv < 2) ? bl : br)[j0 + n16];
    #pragma unroll
    for (int r = 0; r < 4; r++) {
        int node = quad * 4 + r;
        if (nb + node >= N) continue;
        size_t row = (size_t)(nb + node) * 32;
        if (wv < 2) outl[row + j0 + n16] = __float2half(accv[r] + bj);
        else        outr[row + j0 + n16] = accv[r] + bj;
    }
}

// ===== tail: global-GAT gather for the 64 FOCAL dsts only + output head =====
__launch_bounds__(64)
__global__ void k_tailf(const __half* __restrict__ xl, const float* __restrict__ xr,
                        const float* __restrict__ att,
                        const int* __restrict__ offs, const int* __restrict__ csr,
                        const float* __restrict__ gb, const int* __restrict__ focal,
                        const float* __restrict__ clf, const float* __restrict__ clW,
                        const float* __restrict__ clb, const float* __restrict__ fcW,
                        const float* __restrict__ fcb, void* __restrict__ out,
                        const int* __restrict__ flag) {
    __shared__ float comb[64];
    __shared__ float ssb[2];
    int b = blockIdx.x;
    int t = threadIdx.x;                  // 64
    int d = focal[b];
    int grp = t >> 3, sub = t & 7;        // 8 edge-groups x 8 lanes (4 ch each)
    int i0 = offs[d], i1 = offs[d + 1];

    float xrd[4], av[4], acc[4];
    {
        float4 a = *(const float4*)(xr + (size_t)d * 32 + sub * 4);
        xrd[0]=a.x; xrd[1]=a.y; xrd[2]=a.z; xrd[3]=a.w;
        float4 c = *(const float4*)(att + sub * 4);
        av[0]=c.x; av[1]=c.y; av[2]=c.z; av[3]=c.w;
    }
    #pragma unroll
    for (int c = 0; c < 4; c++) acc[c] = 0.f;
    float sm = 0.f;

    for (int i = i0 + grp; i < i1; i += 8) {
        float2 raw = *(const float2*)(xl + (size_t)csr[i] * 32 + sub * 4);
        const __half2* h = (const __half2*)&raw;
        float v[4];
        float2 f;
        f = __half22float2(h[0]); v[0] = f.x; v[1] = f.y;
        f = __half22float2(h[1]); v[2] = f.x; v[3] = f.y;
        float p = 0.f;
        #pragma unroll
        for (int c = 0; c < 4; c++) {
            float u = v[c] + xrd[c];
            u = (u > 0.f) ? u : NEG_SLOPE * u;
            p += u * av[c];
        }
        p += __shfl_xor(p, 1);
        p += __shfl_xor(p, 2);
        p += __shfl_xor(p, 4);
        float w = __expf(fminf(p, 80.f));
        sm += w;
        #pragma unroll
        for (int c = 0; c < 4; c++) acc[c] += w * v[c];
    }
    // merge 8 edge-groups
    sm += __shfl_xor(sm, 8); sm += __shfl_xor(sm, 16); sm += __shfl_xor(sm, 32);
    #pragma unroll
    for (int c = 0; c < 4; c++) {
        acc[c] += __shfl_xor(acc[c], 8);
        acc[c] += __shfl_xor(acc[c], 16);
        acc[c] += __shfl_xor(acc[c], 32);
    }
    if (grp == 0) {
        float inv = 1.f / (sm + 1e-16f);
        #pragma unroll
        for (int c = 0; c < 4; c++)
            comb[sub * 4 + c] = fmaxf(acc[c] * inv + gb[sub * 4 + c], 0.f);
    }
    if (t < 2) {
        float s = 0.f;
        for (int l = 0; l < 50; l++) s += clf[(size_t)b * 100 + l * 2 + t];
        ssb[t] = s / 50.f;
    }
    __syncthreads();
    if (t < 32) comb[32 + t] = ssb[0] * clW[t] + ssb[1] * clW[32 + t] + clb[t];
    __syncthreads();
    if (t < 60) {
        float a2 = fcb[t];
        #pragma unroll 16
        for (int k = 0; k < 64; k++) a2 += comb[k] * fcW[k * 60 + t];
        if (flag[0]) ((float*)out)[b * 60 + t] = a2;
        else ((bf16*)out)[b * 60 + t] = __float2bfloat16(a2);
    }
}

extern "C" void kernel_launch(void* const* d_in, const int* in_sizes, int n_in,
                              void* d_out, int out_size, void* d_ws, size_t ws_size,
                              hipStream_t stream) {
    const int* edge  = (const int*)d_in[1];
    const int* focal = (const int*)d_in[5];

    const int N = in_sizes[0] / 100;   // 20000
    const int E = in_sizes[1] / 2;     // 320000
    const int B = in_sizes[5];         // 64
    const int EA = E + N;
    const int* srcArr = edge;
    const int* dstArr = edge + E;

    // ---- conversion table: weights + centerlines -> fp32 in ws (x stays raw)
    const int idxs[NSEG] = {7,8,9,10,11,12,13,14,15,16,17,18,19,20,
                            35,36,37,38,39,40,41,42,43,44, 6};
    float* base = (float*)d_ws;
    int* flag = (int*)base;            // base[0..15] reserved
    float* wf = base + 16;
    Tab tab;
    int off[NSEG];
    int o = 0;
    for (int i = 0; i < NSEG; i++) {
        tab.s[i].src = d_in[idxs[i]];
        tab.s[i].n   = in_sizes[idxs[i]];
        tab.s[i].off = o;
        off[i] = o;
        o += in_sizes[idxs[i]];
    }
    const float* aeW  = wf + off[0],  *aeb  = wf + off[1];
    const float* a1Wl = wf + off[2],  *a1bl = wf + off[3];
    const float* a1Wr = wf + off[4],  *a1br = wf + off[5];
    const float* a1att= wf + off[6],  *a1b  = wf + off[7];
    const float* a2bl = wf + off[9];
    const float* a2br = wf + off[11];
    const float* a2att= wf + off[12], *a2b  = wf + off[13];
    const float* clW  = wf + off[14], *clb  = wf + off[15];
    const float* gbl  = wf + off[17];
    const float* gbr  = wf + off[19];
    const float* gatt = wf + off[20], *gb   = wf + off[21];
    const float* fcW  = wf + off[22], *fcb  = wf + off[23];
    const float* clf  = wf + off[24];

    // ---- remaining workspace (keep 16B alignment) ----
    float* p = wf + o + ((4 - (o & 3)) & 3);
    size_t N128 = (size_t)N * 128;
    __half* hxl1 = (__half*)p;      p += (size_t)N * 64;    // conv1 xl fp16 [N,128]; later global xl [N,32]
    float* fB1  = p;                p += N128;              // conv1 xr fp32; later global xrg [N,32]
    __half* hxl2 = (__half*)p;      p += (size_t)N * 64;    // conv2 xl fp16 [N,128]
    float* fB2  = p;                p += N128;              // conv2 xr fp32
    int* deg    = (int*)p;          // [N]
    int* st     = deg + N;          // [32] scan lookback state
    int* offs   = st + 32;          // N+1
    int* rank   = offs + N + 1;     // EA
    int* csr    = rank + EA;        // EA (src node ids)
    // transposed f16 weights (16B aligned)
    uintptr_t up = (uintptr_t)(csr + EA);
    up = (up + 15) & ~(uintptr_t)15;
    __half* a2Wlt = (__half*)up;    // [128][128]
    __half* a2Wrt = a2Wlt + 16384;  // [128][128]
    __half* gWlt  = a2Wrt + 16384;  // [32][128]
    __half* gWrt  = gWlt + 4096;    // [32][128]

    const int NB = (N + 1023) / 1024;          // scan tiles (20)
    const int EB = N / 32;                     // embedlin blocks (625)
    const int FBLK = (EA + 255) / 256;         // fill blocks
    const int GT = (N + 15) / 16;              // fused gather+linear tiles (1250)

    // ---- detect + zero deg/st ----
    k_detect_zero<<<64, 256, 0, stream>>>((const unsigned short*)d_in[0], flag, deg, N + 32);
    // ---- convert weights (+ f16 transposed) + degree count with rank capture
    k_convert<<<256, 256, 0, stream>>>(tab, wf, flag, dstArr, E, N, deg, rank,
                                       d_in[15], d_in[17], d_in[37], d_in[39],
                                       a2Wlt, a2Wrt, gWlt, gWrt);
    // ---- single-kernel lookback scan ----
    k_scanf<<<NB, 1024, 0, stream>>>(deg, offs, N, st, NB);
    // ---- CSR fill (rank trick) + fused embed+conv1-linear -> hxl1/fB1 ----
    k_fill_embedlin<<<EB + FBLK, 256, 0, stream>>>(srcArr, dstArr, E, N, offs, rank, csr,
                                                   d_in[0], flag, aeW, aeb,
                                                   a1Wl, a1bl, a1Wr, a1br, hxl1, fB1, EB);
    // ---- conv1 gather + conv2 linear (MFMA, fC stays in LDS) -> hxl2/fB2 ----
    k_gatlin<<<GT, 256, 0, stream>>>(hxl1, fB1, a1att, offs, csr, a1b,
                                     a2Wlt, a2bl, a2Wrt, a2br, hxl2, fB2, N);
    // ---- conv2 gather + global linear (MFMA) -> hxl1([N,32]) / fB1([N,32]) --
    k_gatling<<<GT, 256, 0, stream>>>(hxl2, fB2, a2att, offs, csr, a2b,
                                      gWlt, gbl, gWrt, gbr, hxl1, fB1, N);
    // ---- tail: global gather for the 64 focal dsts + head ----
    k_tailf<<<B, 64, 0, stream>>>(hxl1, fB1, gatt, offs, csr, gb, focal,
                                  clf, clW, clb, fcW, fcb, d_out, flag);
}